// Round 3
// baseline (484.967 us; speedup 1.0000x reference)
//
#include <hip/hip_runtime.h>
#include <stdint.h>

// B=8, C=64, N=4096. Flash attention with Q=K=x^T [N,64], V=x^T W [N,64].
// Round 3: LDS-staged K/V via global_load_lds (width=16, XOR-swizzled chunks),
// wave i-tile 32 (block 128 rows), bf16 P staging. Fixed stabilizer m=||q||^2.

#define NTOK 4096
#define CCH  64

typedef float v4f __attribute__((ext_vector_type(4)));
typedef __bf16 v8bf __attribute__((ext_vector_type(8)));
typedef unsigned short v8us __attribute__((ext_vector_type(8)));

__device__ __forceinline__ unsigned short f2bf(float f) {
    union { float f; unsigned int u; } c; c.f = f;
    unsigned int r = c.u + 0x7fffu + ((c.u >> 16) & 1u);   // RNE
    return (unsigned short)(r >> 16);
}

__device__ __forceinline__ v8bf ld8(const unsigned short* p) {
    union { v8us s; v8bf b; } u;
    u.s = *(const v8us*)p;
    return u.b;
}

// async global->LDS, 16B per lane; LDS dest must be wave-uniform base (+lane*16)
__device__ __forceinline__ void gload_lds16(const void* g, void* l) {
    __builtin_amdgcn_global_load_lds(
        (const __attribute__((address_space(1))) unsigned int*)g,
        (__attribute__((address_space(3))) unsigned int*)l,
        16, 0, 0);
}

// ---------------------------------------------------------------------------
// Prep: xT[b][n][c] = bf16(x[b][c][n]);  sT[b][d][n] = bf16(sum_c x[b][c][n] W[c][d])
// Grid (64, 8) x 256. Block = 64 tokens; 4 d-groups of 16 channels per token.
// ---------------------------------------------------------------------------
__global__ __launch_bounds__(256, 4) void prep_kernel(
    const float* __restrict__ x,        // [8][64][4096]
    const float* __restrict__ w,        // [64][64]
    unsigned short* __restrict__ xT,    // [8][4096][64] bf16
    unsigned short* __restrict__ sT)    // [8][64][4096] bf16
{
    const int tid = threadIdx.x;
    const int b  = blockIdx.y;
    const int nl = tid & 63;
    const int dg = tid >> 6;                 // wave-uniform
    const int n  = blockIdx.x * 64 + nl;
    const float* xb = x + (size_t)b * CCH * NTOK + n;

    float acc[16];
    #pragma unroll
    for (int d = 0; d < 16; ++d) acc[d] = 0.f;
    v8us xrow[8];

    #pragma unroll
    for (int c = 0; c < 64; ++c) {
        float xc = xb[(size_t)c * NTOK];                 // coalesced
        if (dg == 0) xrow[c >> 3][c & 7] = f2bf(xc);
        const float* wr = w + c * 64 + dg * 16;          // scalar (wave-uniform)
        #pragma unroll
        for (int d = 0; d < 16; ++d) acc[d] = fmaf(xc, wr[d], acc[d]);
    }
    unsigned short* stb = sT + (size_t)b * CCH * NTOK + n;
    #pragma unroll
    for (int d = 0; d < 16; ++d)
        stb[(size_t)(dg * 16 + d) * NTOK] = f2bf(acc[d]);    // coalesced
    if (dg == 0) {
        unsigned short* xtr = xT + ((size_t)b * NTOK + n) * CCH;
        #pragma unroll
        for (int k = 0; k < 8; ++k) *(v8us*)(xtr + k * 8) = xrow[k];
    }
}

// ---------------------------------------------------------------------------
// Flash chunk kernel. Grid: (32 i-tiles, KS chunks, 8 batches) x 256 thr.
// Block = 128 Q rows (32/wave, 2 m-tiles). j-tile = 64, K/V staged in LDS.
// LDS tile layout [row][8 chunks of 8 shorts], chunk stored at pos c^(row&7).
// MFMA 16x16x32 bf16: A[m=l16][k=quad*8+j]  B[k=quad*8+j][n=l16]
//                     C/D[row=quad*4+r][col=l16]
// ---------------------------------------------------------------------------
__global__ __launch_bounds__(256, 4) void flash_kernel(
    const unsigned short* __restrict__ xT,   // [8][4096][64]
    const unsigned short* __restrict__ sT,   // [8][64][4096]
    float* __restrict__ part_o,              // [8][KS][4096][64]
    float* __restrict__ part_l,              // [8][KS][4096]
    int nchunk, int chunk_len)
{
    __shared__ __align__(16) unsigned short Kt[64 * 64];     // 8 KB
    __shared__ __align__(16) unsigned short Vt[64 * 64];     // 8 KB
    __shared__ __align__(16) unsigned short Pt[4][32 * 64];  // 16 KB

    const int tid  = threadIdx.x;
    const int w    = tid >> 6;
    const int lane = tid & 63;
    const int quad = lane >> 4;
    const int l16  = lane & 15;
    const int l7   = l16 & 7;
    const int b     = blockIdx.z;
    const int chunk = blockIdx.y;
    const int i0   = blockIdx.x * 128;
    const int irow = i0 + w * 32;
    const int jb   = chunk * chunk_len;

    const unsigned short* xTb = xT + (size_t)b * NTOK * CCH;
    const unsigned short* sTb = sT + (size_t)b * CCH * NTOK;

    // staging geometry: this lane stages row (s*32 + srow), swizzled chunk sc
    const int srow = w * 8 + (lane >> 3);          // 0..31
    const int sc   = (lane & 7) ^ (lane >> 3);     // global chunk to fetch
    unsigned short* kd0 = Kt + w * 512;            // +s*2048 shorts for s=1
    unsigned short* vd0 = Vt + w * 512;

    // Q fragments for 2 m-tiles
    v8bf aq0[2], aq1[2];
    #pragma unroll
    for (int m = 0; m < 2; ++m) {
        const unsigned short* qr = xTb + (size_t)(irow + m * 16 + l16) * CCH + quad * 8;
        aq0[m] = ld8(qr);
        aq1[m] = ld8(qr + 32);
    }

    // fixed stabilizer m = ||q_row||^2 (bitwise identical across chunks)
    float negm[2][4];
    #pragma unroll
    for (int m = 0; m < 2; ++m) {
        float msq = 0.f;
        #pragma unroll
        for (int i = 0; i < 8; ++i) {
            float e0 = (float)aq0[m][i], e1 = (float)aq1[m][i];
            msq = fmaf(e0, e0, msq);
            msq = fmaf(e1, e1, msq);
        }
        msq += __shfl_xor(msq, 16);
        msq += __shfl_xor(msq, 32);
        #pragma unroll
        for (int r = 0; r < 4; ++r) negm[m][r] = -__shfl(msq, quad * 4 + r);
    }

    v4f o[2][4];
    #pragma unroll
    for (int m = 0; m < 2; ++m)
        #pragma unroll
        for (int ct = 0; ct < 4; ++ct) { o[m][ct][0]=0.f; o[m][ct][1]=0.f; o[m][ct][2]=0.f; o[m][ct][3]=0.f; }
    float rsum[2][4] = {{0.f,0.f,0.f,0.f},{0.f,0.f,0.f,0.f}};

    unsigned short* Pw = Pt[w];

    for (int jj = 0; jj < chunk_len; jj += 64) {
        const int j0 = jb + jj;

        // ---- stage K (tokens j0..j0+63, [tok][c]) and V ([d][tok]) ----
        gload_lds16(xTb + (size_t)(j0 + srow) * CCH + sc * 8,       kd0);
        gload_lds16(xTb + (size_t)(j0 + 32 + srow) * CCH + sc * 8,  kd0 + 2048);
        gload_lds16(sTb + (size_t)srow * NTOK + j0 + sc * 8,        vd0);
        gload_lds16(sTb + (size_t)(32 + srow) * NTOK + j0 + sc * 8, vd0 + 2048);
        __syncthreads();   // drains the LDS-DMA (vmcnt) + all waves ready

        // ---- S = Q K^T, exp, stage P (bf16, truncated) ----
        #pragma unroll
        for (int jt = 0; jt < 4; ++jt) {
            const int krow = 16 * jt + l16;
            const unsigned short* kb = Kt + krow * 64;
            const int c0 = quad ^ l7;
            v8bf bk0 = ld8(kb + c0 * 8);
            v8bf bk1 = ld8(kb + (c0 ^ 4) * 8);
            #pragma unroll
            for (int m = 0; m < 2; ++m) {
                v4f z; z[0]=0.f; z[1]=0.f; z[2]=0.f; z[3]=0.f;
                z = __builtin_amdgcn_mfma_f32_16x16x32_bf16(aq0[m], bk0, z, 0, 0, 0);
                z = __builtin_amdgcn_mfma_f32_16x16x32_bf16(aq1[m], bk1, z, 0, 0, 0);
                #pragma unroll
                for (int r = 0; r < 4; ++r) {
                    float p = __expf(z[r] + negm[m][r]);
                    rsum[m][r] += p;
                    const int row_p = m * 16 + quad * 4 + r;
                    const int cs = (2 * jt + (l16 >> 3)) ^ (row_p & 7);
                    union { float f; unsigned int u; } cv; cv.f = p;
                    Pw[row_p * 64 + cs * 8 + l7] = (unsigned short)(cv.u >> 16);
                }
            }
        }

        // ---- read P in A-layout (wave-local; lgkmcnt ordering only) ----
        v8bf ap0[2], ap1[2];
        #pragma unroll
        for (int m = 0; m < 2; ++m) {
            const unsigned short* pr = Pw + (m * 16 + l16) * 64;
            const int p0 = quad ^ l7;
            ap0[m] = ld8(pr + p0 * 8);
            ap1[m] = ld8(pr + (p0 ^ 4) * 8);
        }

        // ---- O += P V ----
        #pragma unroll
        for (int ct = 0; ct < 4; ++ct) {
            const int vrow = 16 * ct + l16;
            const unsigned short* vb = Vt + vrow * 64;
            const int c0 = quad ^ l7;
            v8bf bv0 = ld8(vb + c0 * 8);
            v8bf bv1 = ld8(vb + (c0 ^ 4) * 8);
            #pragma unroll
            for (int m = 0; m < 2; ++m) {
                o[m][ct] = __builtin_amdgcn_mfma_f32_16x16x32_bf16(ap0[m], bv0, o[m][ct], 0, 0, 0);
                o[m][ct] = __builtin_amdgcn_mfma_f32_16x16x32_bf16(ap1[m], bv1, o[m][ct], 0, 0, 0);
            }
        }
        __syncthreads();   // all reads of Kt/Vt done before next staging
    }

    // ---- epilogue: reduce row sums, store partials ----
    const size_t pbase = (size_t)(b * nchunk + chunk) * NTOK + irow;
    #pragma unroll
    for (int m = 0; m < 2; ++m) {
        #pragma unroll
        for (int r = 0; r < 4; ++r) {
            float t = rsum[m][r];
            t += __shfl_xor(t, 1);
            t += __shfl_xor(t, 2);
            t += __shfl_xor(t, 4);
            t += __shfl_xor(t, 8);
            if (l16 == 0) part_l[pbase + m * 16 + quad * 4 + r] = t;
        }
    }
    float* po = part_o + pbase * 64;
    #pragma unroll
    for (int m = 0; m < 2; ++m)
        #pragma unroll
        for (int ct = 0; ct < 4; ++ct)
            #pragma unroll
            for (int r = 0; r < 4; ++r)
                po[(size_t)(m * 16 + quad * 4 + r) * 64 + 16 * ct + l16] = o[m][ct][r];
}

// ---------------------------------------------------------------------------
// Combine: sum chunk partials, normalize, transpose, add x, store.
// Grid: (64 i-tiles, 8 batches) x 256 threads.
// ---------------------------------------------------------------------------
__global__ __launch_bounds__(256, 2) void combine_kernel(
    const float* __restrict__ part_o,  // [8][KS][4096][64]
    const float* __restrict__ part_l,  // [8][KS][4096]
    const float* __restrict__ x,       // [8][64][4096]
    float* __restrict__ out,           // [8][64][4096]
    int nchunk)
{
    __shared__ float Of[64 * 65];
    const int tid = threadIdx.x;
    const int b = blockIdx.y;
    const int i0 = blockIdx.x * 64;
    const int row = tid >> 2;          // local n 0..63
    const int seg = tid & 3;           // 16-col segment

    float acc[16];
    #pragma unroll
    for (int k = 0; k < 16; ++k) acc[k] = 0.f;
    float lt = 0.f;

    for (int ch = 0; ch < nchunk; ++ch) {
        const size_t base = (size_t)(b * nchunk + ch) * NTOK + i0 + row;
        lt += part_l[base];
        const float* po = part_o + base * 64 + seg * 16;
        #pragma unroll
        for (int k = 0; k < 4; ++k) {
            float4 v = *(const float4*)(po + k * 4);
            acc[k*4+0] += v.x; acc[k*4+1] += v.y; acc[k*4+2] += v.z; acc[k*4+3] += v.w;
        }
    }
    const float inv = 1.f / lt;
    #pragma unroll
    for (int k = 0; k < 16; ++k) Of[row * 65 + seg * 16 + k] = acc[k] * inv;
    __syncthreads();

    const int c    = tid >> 2;
    const int part = tid & 3;
    const float* xrow = x   + ((size_t)b * CCH + c) * NTOK + i0 + part * 16;
    float*       orow = out + ((size_t)b * CCH + c) * NTOK + i0 + part * 16;
    #pragma unroll
    for (int i4 = 0; i4 < 4; ++i4) {
        float4 xv = *(const float4*)(xrow + i4 * 4);
        float4 ov;
        ov.x = Of[(part * 16 + i4 * 4 + 0) * 65 + c] + xv.x;
        ov.y = Of[(part * 16 + i4 * 4 + 1) * 65 + c] + xv.y;
        ov.z = Of[(part * 16 + i4 * 4 + 2) * 65 + c] + xv.z;
        ov.w = Of[(part * 16 + i4 * 4 + 3) * 65 + c] + xv.w;
        *(float4*)(orow + i4 * 4) = ov;
    }
}

// ---------------------------------------------------------------------------
extern "C" void kernel_launch(void* const* d_in, const int* in_sizes, int n_in,
                              void* d_out, int out_size, void* d_ws, size_t ws_size,
                              hipStream_t stream) {
    const float* x = (const float*)d_in[0];
    const float* w = (const float*)d_in[1];
    float* out = (float*)d_out;

    const size_t xT_elems = (size_t)8 * NTOK * CCH;         // 2M shorts = 4 MB
    unsigned short* xT = (unsigned short*)d_ws;
    unsigned short* sT = xT + xT_elems;
    char* rest = (char*)d_ws + 2 * xT_elems * sizeof(unsigned short);   // +8 MB

    int KS = 4;
    while (KS > 1) {
        size_t need = 2 * xT_elems * sizeof(unsigned short)
                    + (size_t)KS * ((size_t)8 * NTOK * CCH * 4 + (size_t)8 * NTOK * 4);
        if (need <= ws_size) break;
        KS >>= 1;
    }
    float* part_o = (float*)rest;
    float* part_l = (float*)(rest + (size_t)KS * 8 * NTOK * CCH * 4);

    dim3 gp(64, 8);
    prep_kernel<<<gp, 256, 0, stream>>>(x, w, xT, sT);
    dim3 gf(32, KS, 8);
    flash_kernel<<<gf, 256, 0, stream>>>(xT, sT, part_o, part_l, KS, NTOK / KS);
    dim3 gc(64, 8);
    combine_kernel<<<gc, 256, 0, stream>>>(part_o, part_l, x, out, KS);
}

// Round 4
// 135.980 us; speedup vs baseline: 3.5665x; 3.5665x over previous
//
#include <hip/hip_runtime.h>
#include <stdint.h>

// B=8, C=64, N=4096. Flash attention with Q=K=x^T [N,64], V=x^T W [N,64].
// Round 4: fix prep scratch-spill (R3: 780 MB phantom traffic, VALUBusy 0.015%).
// Prep now: LDS f32 x-tile [c][n] stride 65; W via readfirstlane-forced scalar
// loads (s_load -> v_fmac with SGPR operand); acc[16] only. Flash unchanged.

#define NTOK 4096
#define CCH  64

typedef float v4f __attribute__((ext_vector_type(4)));
typedef __bf16 v8bf __attribute__((ext_vector_type(8)));
typedef unsigned short v8us __attribute__((ext_vector_type(8)));

__device__ __forceinline__ unsigned short f2bf(float f) {
    union { float f; unsigned int u; } c; c.f = f;
    unsigned int r = c.u + 0x7fffu + ((c.u >> 16) & 1u);   // RNE
    return (unsigned short)(r >> 16);
}

__device__ __forceinline__ v8bf ld8(const unsigned short* p) {
    union { v8us s; v8bf b; } u;
    u.s = *(const v8us*)p;
    return u.b;
}

// async global->LDS, 16B per lane; LDS dest must be wave-uniform base (+lane*16)
__device__ __forceinline__ void gload_lds16(const void* g, void* l) {
    __builtin_amdgcn_global_load_lds(
        (const __attribute__((address_space(1))) unsigned int*)g,
        (__attribute__((address_space(3))) unsigned int*)l,
        16, 0, 0);
}

// ---------------------------------------------------------------------------
// Prep: xT[b][n][c] = bf16(x[b][c][n]);  sT[b][d][n] = bf16(sum_c x[b][c][n] W[c][d])
// Grid (64, 8) x 256. Block = 64 tokens. Wave wv owns d-range [wv*16, wv*16+16).
// ---------------------------------------------------------------------------
__global__ __launch_bounds__(256) void prep_kernel(
    const float* __restrict__ x,        // [8][64][4096]
    const float* __restrict__ w,        // [64][64]
    unsigned short* __restrict__ xT,    // [8][4096][64] bf16
    unsigned short* __restrict__ sT)    // [8][64][4096] bf16
{
    __shared__ float Xf[64 * 65];       // [c][n], stride 65 (bank-spread)

    const int tid  = threadIdx.x;
    const int lane = tid & 63;
    const int wv   = __builtin_amdgcn_readfirstlane(tid >> 6);  // wave-uniform
    const int b    = blockIdx.y;
    const int n0   = blockIdx.x * 64;

    // ---- stage x tile [64 c][64 n] f32 into LDS (coalesced global reads) ----
    const float* xb = x + (size_t)b * CCH * NTOK + n0 + lane;
    #pragma unroll
    for (int k = 0; k < 16; ++k) {
        const int c = wv * 16 + k;
        Xf[c * 65 + lane] = xb[(size_t)c * NTOK];
    }
    __syncthreads();

    // ---- write xT[n][c] bf16: thread -> n = tid>>2, c-chunk = (tid&3)*16 ----
    {
        const int n  = tid >> 2;
        const int c0 = (tid & 3) * 16;
        unsigned int pk[8];
        #pragma unroll
        for (int k = 0; k < 8; ++k) {
            const float a = Xf[(c0 + 2 * k) * 65 + n];
            const float c2 = Xf[(c0 + 2 * k + 1) * 65 + n];
            pk[k] = (unsigned int)f2bf(a) | ((unsigned int)f2bf(c2) << 16);
        }
        unsigned short* xtr = xT + ((size_t)b * NTOK + n0 + n) * CCH + c0;
        *(uint4*)(xtr)     = *(uint4*)(pk);
        *(uint4*)(xtr + 8) = *(uint4*)(pk + 4);
    }

    // ---- support: lane's token n0+lane, d in [wv*16, wv*16+16) ----
    float acc[16];
    #pragma unroll
    for (int d = 0; d < 16; ++d) acc[d] = 0.f;

    #pragma unroll 4
    for (int c = 0; c < 64; ++c) {
        const float xc = Xf[c * 65 + lane];
        const float* wr = w + c * 64 + wv * 16;      // scalar address -> s_load
        #pragma unroll
        for (int d = 0; d < 16; ++d) acc[d] = fmaf(xc, wr[d], acc[d]);
    }
    unsigned short* stb = sT + (size_t)b * CCH * NTOK + n0 + lane;
    #pragma unroll
    for (int d = 0; d < 16; ++d)
        stb[(size_t)(wv * 16 + d) * NTOK] = f2bf(acc[d]);    // coalesced
}

// ---------------------------------------------------------------------------
// Flash chunk kernel. Grid: (32 i-tiles, KS chunks, 8 batches) x 256 thr.
// Block = 128 Q rows (32/wave, 2 m-tiles). j-tile = 64, K/V staged in LDS.
// LDS tile layout [row][8 chunks of 8 shorts], chunk stored at pos c^(row&7).
// MFMA 16x16x32 bf16: A[m=l16][k=quad*8+j]  B[k=quad*8+j][n=l16]
//                     C/D[row=quad*4+r][col=l16]
// ---------------------------------------------------------------------------
__global__ __launch_bounds__(256, 4) void flash_kernel(
    const unsigned short* __restrict__ xT,   // [8][4096][64]
    const unsigned short* __restrict__ sT,   // [8][64][4096]
    float* __restrict__ part_o,              // [8][KS][4096][64]
    float* __restrict__ part_l,              // [8][KS][4096]
    int nchunk, int chunk_len)
{
    __shared__ __align__(16) unsigned short Kt[64 * 64];     // 8 KB
    __shared__ __align__(16) unsigned short Vt[64 * 64];     // 8 KB
    __shared__ __align__(16) unsigned short Pt[4][32 * 64];  // 16 KB

    const int tid  = threadIdx.x;
    const int w    = tid >> 6;
    const int lane = tid & 63;
    const int quad = lane >> 4;
    const int l16  = lane & 15;
    const int l7   = l16 & 7;
    const int b     = blockIdx.z;
    const int chunk = blockIdx.y;
    const int i0   = blockIdx.x * 128;
    const int irow = i0 + w * 32;
    const int jb   = chunk * chunk_len;

    const unsigned short* xTb = xT + (size_t)b * NTOK * CCH;
    const unsigned short* sTb = sT + (size_t)b * CCH * NTOK;

    // staging geometry: this lane stages row (s*32 + srow), swizzled chunk sc
    const int srow = w * 8 + (lane >> 3);          // 0..31
    const int sc   = (lane & 7) ^ (lane >> 3);     // global chunk to fetch
    unsigned short* kd0 = Kt + w * 512;            // +s*2048 shorts for s=1
    unsigned short* vd0 = Vt + w * 512;

    // Q fragments for 2 m-tiles
    v8bf aq0[2], aq1[2];
    #pragma unroll
    for (int m = 0; m < 2; ++m) {
        const unsigned short* qr = xTb + (size_t)(irow + m * 16 + l16) * CCH + quad * 8;
        aq0[m] = ld8(qr);
        aq1[m] = ld8(qr + 32);
    }

    // fixed stabilizer m = ||q_row||^2 (bitwise identical across chunks)
    float negm[2][4];
    #pragma unroll
    for (int m = 0; m < 2; ++m) {
        float msq = 0.f;
        #pragma unroll
        for (int i = 0; i < 8; ++i) {
            float e0 = (float)aq0[m][i], e1 = (float)aq1[m][i];
            msq = fmaf(e0, e0, msq);
            msq = fmaf(e1, e1, msq);
        }
        msq += __shfl_xor(msq, 16);
        msq += __shfl_xor(msq, 32);
        #pragma unroll
        for (int r = 0; r < 4; ++r) negm[m][r] = -__shfl(msq, quad * 4 + r);
    }

    v4f o[2][4];
    #pragma unroll
    for (int m = 0; m < 2; ++m)
        #pragma unroll
        for (int ct = 0; ct < 4; ++ct) { o[m][ct][0]=0.f; o[m][ct][1]=0.f; o[m][ct][2]=0.f; o[m][ct][3]=0.f; }
    float rsum[2][4] = {{0.f,0.f,0.f,0.f},{0.f,0.f,0.f,0.f}};

    unsigned short* Pw = Pt[w];

    for (int jj = 0; jj < chunk_len; jj += 64) {
        const int j0 = jb + jj;

        // ---- stage K (tokens j0..j0+63, [tok][c]) and V ([d][tok]) ----
        gload_lds16(xTb + (size_t)(j0 + srow) * CCH + sc * 8,       kd0);
        gload_lds16(xTb + (size_t)(j0 + 32 + srow) * CCH + sc * 8,  kd0 + 2048);
        gload_lds16(sTb + (size_t)srow * NTOK + j0 + sc * 8,        vd0);
        gload_lds16(sTb + (size_t)(32 + srow) * NTOK + j0 + sc * 8, vd0 + 2048);
        __syncthreads();   // drains the LDS-DMA (vmcnt) + all waves ready

        // ---- S = Q K^T, exp, stage P (bf16, truncated) ----
        #pragma unroll
        for (int jt = 0; jt < 4; ++jt) {
            const int krow = 16 * jt + l16;
            const unsigned short* kb = Kt + krow * 64;
            const int c0 = quad ^ l7;
            v8bf bk0 = ld8(kb + c0 * 8);
            v8bf bk1 = ld8(kb + (c0 ^ 4) * 8);
            #pragma unroll
            for (int m = 0; m < 2; ++m) {
                v4f z; z[0]=0.f; z[1]=0.f; z[2]=0.f; z[3]=0.f;
                z = __builtin_amdgcn_mfma_f32_16x16x32_bf16(aq0[m], bk0, z, 0, 0, 0);
                z = __builtin_amdgcn_mfma_f32_16x16x32_bf16(aq1[m], bk1, z, 0, 0, 0);
                #pragma unroll
                for (int r = 0; r < 4; ++r) {
                    float p = __expf(z[r] + negm[m][r]);
                    rsum[m][r] += p;
                    const int row_p = m * 16 + quad * 4 + r;
                    const int cs = (2 * jt + (l16 >> 3)) ^ (row_p & 7);
                    union { float f; unsigned int u; } cv; cv.f = p;
                    Pw[row_p * 64 + cs * 8 + l7] = (unsigned short)(cv.u >> 16);
                }
            }
        }

        // ---- read P in A-layout (wave-local; lgkmcnt ordering only) ----
        v8bf ap0[2], ap1[2];
        #pragma unroll
        for (int m = 0; m < 2; ++m) {
            const unsigned short* pr = Pw + (m * 16 + l16) * 64;
            const int p0 = quad ^ l7;
            ap0[m] = ld8(pr + p0 * 8);
            ap1[m] = ld8(pr + (p0 ^ 4) * 8);
        }

        // ---- O += P V ----
        #pragma unroll
        for (int ct = 0; ct < 4; ++ct) {
            const int vrow = 16 * ct + l16;
            const unsigned short* vb = Vt + vrow * 64;
            const int c0 = quad ^ l7;
            v8bf bv0 = ld8(vb + c0 * 8);
            v8bf bv1 = ld8(vb + (c0 ^ 4) * 8);
            #pragma unroll
            for (int m = 0; m < 2; ++m) {
                o[m][ct] = __builtin_amdgcn_mfma_f32_16x16x32_bf16(ap0[m], bv0, o[m][ct], 0, 0, 0);
                o[m][ct] = __builtin_amdgcn_mfma_f32_16x16x32_bf16(ap1[m], bv1, o[m][ct], 0, 0, 0);
            }
        }
        __syncthreads();   // all reads of Kt/Vt done before next staging
    }

    // ---- epilogue: reduce row sums, store partials ----
    const size_t pbase = (size_t)(b * nchunk + chunk) * NTOK + irow;
    #pragma unroll
    for (int m = 0; m < 2; ++m) {
        #pragma unroll
        for (int r = 0; r < 4; ++r) {
            float t = rsum[m][r];
            t += __shfl_xor(t, 1);
            t += __shfl_xor(t, 2);
            t += __shfl_xor(t, 4);
            t += __shfl_xor(t, 8);
            if (l16 == 0) part_l[pbase + m * 16 + quad * 4 + r] = t;
        }
    }
    float* po = part_o + pbase * 64;
    #pragma unroll
    for (int m = 0; m < 2; ++m)
        #pragma unroll
        for (int ct = 0; ct < 4; ++ct)
            #pragma unroll
            for (int r = 0; r < 4; ++r)
                po[(size_t)(m * 16 + quad * 4 + r) * 64 + 16 * ct + l16] = o[m][ct][r];
}

// ---------------------------------------------------------------------------
// Combine: sum chunk partials, normalize, transpose, add x, store.
// Grid: (64 i-tiles, 8 batches) x 256 threads.
// ---------------------------------------------------------------------------
__global__ __launch_bounds__(256, 2) void combine_kernel(
    const float* __restrict__ part_o,  // [8][KS][4096][64]
    const float* __restrict__ part_l,  // [8][KS][4096]
    const float* __restrict__ x,       // [8][64][4096]
    float* __restrict__ out,           // [8][64][4096]
    int nchunk)
{
    __shared__ float Of[64 * 65];
    const int tid = threadIdx.x;
    const int b = blockIdx.y;
    const int i0 = blockIdx.x * 64;
    const int row = tid >> 2;          // local n 0..63
    const int seg = tid & 3;           // 16-col segment

    float acc[16];
    #pragma unroll
    for (int k = 0; k < 16; ++k) acc[k] = 0.f;
    float lt = 0.f;

    for (int ch = 0; ch < nchunk; ++ch) {
        const size_t base = (size_t)(b * nchunk + ch) * NTOK + i0 + row;
        lt += part_l[base];
        const float* po = part_o + base * 64 + seg * 16;
        #pragma unroll
        for (int k = 0; k < 4; ++k) {
            float4 v = *(const float4*)(po + k * 4);
            acc[k*4+0] += v.x; acc[k*4+1] += v.y; acc[k*4+2] += v.z; acc[k*4+3] += v.w;
        }
    }
    const float inv = 1.f / lt;
    #pragma unroll
    for (int k = 0; k < 16; ++k) Of[row * 65 + seg * 16 + k] = acc[k] * inv;
    __syncthreads();

    const int c    = tid >> 2;
    const int part = tid & 3;
    const float* xrow = x   + ((size_t)b * CCH + c) * NTOK + i0 + part * 16;
    float*       orow = out + ((size_t)b * CCH + c) * NTOK + i0 + part * 16;
    #pragma unroll
    for (int i4 = 0; i4 < 4; ++i4) {
        float4 xv = *(const float4*)(xrow + i4 * 4);
        float4 ov;
        ov.x = Of[(part * 16 + i4 * 4 + 0) * 65 + c] + xv.x;
        ov.y = Of[(part * 16 + i4 * 4 + 1) * 65 + c] + xv.y;
        ov.z = Of[(part * 16 + i4 * 4 + 2) * 65 + c] + xv.z;
        ov.w = Of[(part * 16 + i4 * 4 + 3) * 65 + c] + xv.w;
        *(float4*)(orow + i4 * 4) = ov;
    }
}

// ---------------------------------------------------------------------------
extern "C" void kernel_launch(void* const* d_in, const int* in_sizes, int n_in,
                              void* d_out, int out_size, void* d_ws, size_t ws_size,
                              hipStream_t stream) {
    const float* x = (const float*)d_in[0];
    const float* w = (const float*)d_in[1];
    float* out = (float*)d_out;

    const size_t xT_elems = (size_t)8 * NTOK * CCH;         // 2M shorts = 4 MB
    unsigned short* xT = (unsigned short*)d_ws;
    unsigned short* sT = xT + xT_elems;
    char* rest = (char*)d_ws + 2 * xT_elems * sizeof(unsigned short);   // +8 MB

    int KS = 4;
    while (KS > 1) {
        size_t need = 2 * xT_elems * sizeof(unsigned short)
                    + (size_t)KS * ((size_t)8 * NTOK * CCH * 4 + (size_t)8 * NTOK * 4);
        if (need <= ws_size) break;
        KS >>= 1;
    }
    float* part_o = (float*)rest;
    float* part_l = (float*)(rest + (size_t)KS * 8 * NTOK * CCH * 4);

    dim3 gp(64, 8);
    prep_kernel<<<gp, 256, 0, stream>>>(x, w, xT, sT);
    dim3 gf(32, KS, 8);
    flash_kernel<<<gf, 256, 0, stream>>>(xT, sT, part_o, part_l, KS, NTOK / KS);
    dim3 gc(64, 8);
    combine_kernel<<<gc, 256, 0, stream>>>(part_o, part_l, x, out, KS);
}

// Round 5
// 125.909 us; speedup vs baseline: 3.8517x; 1.0800x over previous
//
#include <hip/hip_runtime.h>
#include <stdint.h>

// B=8, C=64, N=4096. Flash attention with Q=K=x^T [N,64], V=x^T W [N,64].
// Round 5: S^T formulation. QK^T computed as S^T = K·Q^T (operand swap) so
// C-layout gives j=quad*4+r, i=l16: exp results pack into ds_write_b64 (8/iter
// vs 32 b16), stabilizer/rsum become per-lane, PV as O^T = V^T·P^T, epilogue
// is float4 stores. K/V/P reads keep the measured-conflict-free chunk-XOR.

#define NTOK 4096
#define CCH  64

typedef float v4f __attribute__((ext_vector_type(4)));
typedef __bf16 v8bf __attribute__((ext_vector_type(8)));
typedef unsigned short v8us __attribute__((ext_vector_type(8)));

__device__ __forceinline__ unsigned short f2bf(float f) {
    union { float f; unsigned int u; } c; c.f = f;
    unsigned int r = c.u + 0x7fffu + ((c.u >> 16) & 1u);   // RNE
    return (unsigned short)(r >> 16);
}

__device__ __forceinline__ v8bf ld8(const unsigned short* p) {
    union { v8us s; v8bf b; } u;
    u.s = *(const v8us*)p;
    return u.b;
}

// pack two f32 -> u32 of (bf16_trunc(a) | bf16_trunc(b)<<16), one v_perm
__device__ __forceinline__ unsigned int pkbf(float a, float b) {
    union { float f; unsigned int u; } ua, ub; ua.f = a; ub.f = b;
    return __builtin_amdgcn_perm(ub.u, ua.u, 0x07060302u);
}

// async global->LDS, 16B per lane; LDS dest = wave-uniform base + lane*16
__device__ __forceinline__ void gload_lds16(const void* g, void* l) {
    __builtin_amdgcn_global_load_lds(
        (const __attribute__((address_space(1))) unsigned int*)g,
        (__attribute__((address_space(3))) unsigned int*)l,
        16, 0, 0);
}

// ---------------------------------------------------------------------------
// Prep: xT[b][n][c] = bf16(x[b][c][n]);  sT[b][d][n] = bf16(sum_c x[b][c][n] W[c][d])
// Grid (64, 8) x 256. Block = 64 tokens. Wave wv owns d-range [wv*16, wv*16+16).
// ---------------------------------------------------------------------------
__global__ __launch_bounds__(256) void prep_kernel(
    const float* __restrict__ x,        // [8][64][4096]
    const float* __restrict__ w,        // [64][64]
    unsigned short* __restrict__ xT,    // [8][4096][64] bf16
    unsigned short* __restrict__ sT)    // [8][64][4096] bf16
{
    __shared__ float Xf[64 * 65];       // [c][n], stride 65 (bank-spread)

    const int tid  = threadIdx.x;
    const int lane = tid & 63;
    const int wv   = __builtin_amdgcn_readfirstlane(tid >> 6);  // wave-uniform
    const int b    = blockIdx.y;
    const int n0   = blockIdx.x * 64;

    // ---- stage x tile [64 c][64 n] f32 into LDS (coalesced global reads) ----
    const float* xb = x + (size_t)b * CCH * NTOK + n0 + lane;
    #pragma unroll
    for (int k = 0; k < 16; ++k) {
        const int c = wv * 16 + k;
        Xf[c * 65 + lane] = xb[(size_t)c * NTOK];
    }
    __syncthreads();

    // ---- write xT[n][c] bf16: thread -> n = tid>>2, c-chunk = (tid&3)*16 ----
    {
        const int n  = tid >> 2;
        const int c0 = (tid & 3) * 16;
        unsigned int pk[8];
        #pragma unroll
        for (int k = 0; k < 8; ++k) {
            const float a = Xf[(c0 + 2 * k) * 65 + n];
            const float c2 = Xf[(c0 + 2 * k + 1) * 65 + n];
            pk[k] = (unsigned int)f2bf(a) | ((unsigned int)f2bf(c2) << 16);
        }
        unsigned short* xtr = xT + ((size_t)b * NTOK + n0 + n) * CCH + c0;
        *(uint4*)(xtr)     = *(uint4*)(pk);
        *(uint4*)(xtr + 8) = *(uint4*)(pk + 4);
    }

    // ---- support: lane's token n0+lane, d in [wv*16, wv*16+16) ----
    float acc[16];
    #pragma unroll
    for (int d = 0; d < 16; ++d) acc[d] = 0.f;

    #pragma unroll 4
    for (int c = 0; c < 64; ++c) {
        const float xc = Xf[c * 65 + lane];
        const float* wr = w + c * 64 + wv * 16;      // scalar address -> s_load
        #pragma unroll
        for (int d = 0; d < 16; ++d) acc[d] = fmaf(xc, wr[d], acc[d]);
    }
    unsigned short* stb = sT + (size_t)b * CCH * NTOK + n0 + lane;
    #pragma unroll
    for (int d = 0; d < 16; ++d)
        stb[(size_t)(wv * 16 + d) * NTOK] = f2bf(acc[d]);    // coalesced
}

// ---------------------------------------------------------------------------
// Flash chunk kernel. Grid: (32 i-tiles, KS chunks, 8 batches) x 256 thr.
// Block = 128 Q rows (32/wave, 2 m-tiles). j-tile = 64, K/V staged in LDS.
// S^T = K·Q^T via mfma(K_frag, Q_frag): D[row=j_loc=quad*4+r][col=i_loc=l16].
// P^T stored in LDS [i][j] (stride 64, 8-short chunks at pos = chunk^(i&7)).
// O^T = V^T·P^T: D[row=d_loc][col=i_loc]; epilogue float4 per (m,ct).
// ---------------------------------------------------------------------------
__global__ __launch_bounds__(256, 4) void flash_kernel(
    const unsigned short* __restrict__ xT,   // [8][4096][64]
    const unsigned short* __restrict__ sT,   // [8][64][4096]
    float* __restrict__ part_o,              // [8][KS][4096][64]
    float* __restrict__ part_l,              // [8][KS][4096]
    int nchunk, int chunk_len)
{
    __shared__ __align__(16) unsigned short Kt[64 * 64];     // 8 KB
    __shared__ __align__(16) unsigned short Vt[64 * 64];     // 8 KB
    __shared__ __align__(16) unsigned short Pt[4][32 * 64];  // 16 KB

    const int tid  = threadIdx.x;
    const int w    = tid >> 6;
    const int lane = tid & 63;
    const int quad = lane >> 4;
    const int l16  = lane & 15;
    const int l7   = l16 & 7;
    const int b     = blockIdx.z;
    const int chunk = blockIdx.y;
    const int i0   = blockIdx.x * 128;
    const int irow = i0 + w * 32;
    const int jb   = chunk * chunk_len;

    const unsigned short* xTb = xT + (size_t)b * NTOK * CCH;
    const unsigned short* sTb = sT + (size_t)b * CCH * NTOK;

    // staging geometry: lane stages row (s*32 + srow), swizzled chunk sc
    const int srow = w * 8 + (lane >> 3);          // 0..31
    const int sc   = (lane & 7) ^ (lane >> 3);     // global chunk to fetch
    unsigned short* kd0 = Kt + w * 512;
    unsigned short* vd0 = Vt + w * 512;

    // Q fragments (B-operand of S^T): lane holds Q[irow+m*16+l16][quad*8+..]
    v8bf aq0[2], aq1[2];
    #pragma unroll
    for (int m = 0; m < 2; ++m) {
        const unsigned short* qr = xTb + (size_t)(irow + m * 16 + l16) * CCH + quad * 8;
        aq0[m] = ld8(qr);
        aq1[m] = ld8(qr + 32);
    }

    // fixed stabilizer: negm[m] = -||q_i||^2 for i = m*16+l16 (lane's own col)
    float negm[2];
    #pragma unroll
    for (int m = 0; m < 2; ++m) {
        float msq = 0.f;
        #pragma unroll
        for (int i = 0; i < 8; ++i) {
            float e0 = (float)aq0[m][i], e1 = (float)aq1[m][i];
            msq = fmaf(e0, e0, msq);
            msq = fmaf(e1, e1, msq);
        }
        msq += __shfl_xor(msq, 16);
        msq += __shfl_xor(msq, 32);
        negm[m] = -msq;
    }

    v4f o[2][4];        // o[m][ct]: O^T tile rows d=ct*16+quad*4+r, col i=m*16+l16
    #pragma unroll
    for (int m = 0; m < 2; ++m)
        #pragma unroll
        for (int ct = 0; ct < 4; ++ct) { o[m][ct][0]=0.f; o[m][ct][1]=0.f; o[m][ct][2]=0.f; o[m][ct][3]=0.f; }
    float rsum[2] = {0.f, 0.f};

    unsigned short* Pw = Pt[w];
    const int phalf = (quad & 1) * 4;              // 4-short half within chunk
    const int pgq   = quad >> 1;                   // chunk bit from quad

    for (int jj = 0; jj < chunk_len; jj += 64) {
        const int j0 = jb + jj;

        // ---- stage K ([tok][c]) and V ([d][tok]) ----
        gload_lds16(xTb + (size_t)(j0 + srow) * CCH + sc * 8,       kd0);
        gload_lds16(xTb + (size_t)(j0 + 32 + srow) * CCH + sc * 8,  kd0 + 2048);
        gload_lds16(sTb + (size_t)srow * NTOK + j0 + sc * 8,        vd0);
        gload_lds16(sTb + (size_t)(32 + srow) * NTOK + j0 + sc * 8, vd0 + 2048);
        __syncthreads();

        // ---- S^T = K Q^T, exp, pack, b64-store P^T ----
        #pragma unroll
        for (int jt = 0; jt < 4; ++jt) {
            const int krow = 16 * jt + l16;
            const unsigned short* kb = Kt + krow * 64;
            const int c0 = quad ^ (krow & 7);
            v8bf bk0 = ld8(kb + c0 * 8);
            v8bf bk1 = ld8(kb + (c0 ^ 4) * 8);
            #pragma unroll
            for (int m = 0; m < 2; ++m) {
                v4f z; z[0]=0.f; z[1]=0.f; z[2]=0.f; z[3]=0.f;
                z = __builtin_amdgcn_mfma_f32_16x16x32_bf16(bk0, aq0[m], z, 0, 0, 0);
                z = __builtin_amdgcn_mfma_f32_16x16x32_bf16(bk1, aq1[m], z, 0, 0, 0);
                const float p0 = __expf(z[0] + negm[m]);
                const float p1 = __expf(z[1] + negm[m]);
                const float p2 = __expf(z[2] + negm[m]);
                const float p3 = __expf(z[3] + negm[m]);
                rsum[m] += (p0 + p1) + (p2 + p3);
                uint2 pk; pk.x = pkbf(p0, p1); pk.y = pkbf(p2, p3);
                // row i = m*16+l16; j = 16*jt + quad*4 + r -> chunk g=2jt+(quad>>1)
                const int pos = (2 * jt + pgq) ^ l7;
                *(uint2*)(Pw + (m * 16 + l16) * 64 + pos * 8 + phalf) = pk;
            }
        }

        // ---- P^T B-frags (wave-local; lgkmcnt ordering only) ----
        v8bf pb0[2], pb1[2];
        #pragma unroll
        for (int m = 0; m < 2; ++m) {
            const unsigned short* pr = Pw + (m * 16 + l16) * 64;
            const int p0c = quad ^ l7;
            pb0[m] = ld8(pr + p0c * 8);
            pb1[m] = ld8(pr + (p0c ^ 4) * 8);
        }

        // ---- O^T += V^T P^T ----
        #pragma unroll
        for (int ct = 0; ct < 4; ++ct) {
            const int vrow = 16 * ct + l16;
            const unsigned short* vb = Vt + vrow * 64;
            const int c0 = quad ^ (vrow & 7);
            v8bf bv0 = ld8(vb + c0 * 8);
            v8bf bv1 = ld8(vb + (c0 ^ 4) * 8);
            #pragma unroll
            for (int m = 0; m < 2; ++m) {
                o[m][ct] = __builtin_amdgcn_mfma_f32_16x16x32_bf16(bv0, pb0[m], o[m][ct], 0, 0, 0);
                o[m][ct] = __builtin_amdgcn_mfma_f32_16x16x32_bf16(bv1, pb1[m], o[m][ct], 0, 0, 0);
            }
        }
        __syncthreads();
    }

    // ---- epilogue ----
    const size_t pbase = (size_t)(b * nchunk + chunk) * NTOK + irow;
    #pragma unroll
    for (int m = 0; m < 2; ++m) {
        float t = rsum[m];
        t += __shfl_xor(t, 16);
        t += __shfl_xor(t, 32);
        if (quad == 0) part_l[pbase + m * 16 + l16] = t;
    }
    float* po = part_o + pbase * 64;
    #pragma unroll
    for (int m = 0; m < 2; ++m)
        #pragma unroll
        for (int ct = 0; ct < 4; ++ct)
            *(v4f*)(po + (size_t)(m * 16 + l16) * 64 + ct * 16 + quad * 4) = o[m][ct];
}

// ---------------------------------------------------------------------------
// Combine: sum chunk partials, normalize, transpose, add x, store.
// Grid: (64 i-tiles, 8 batches) x 256 threads.
// ---------------------------------------------------------------------------
__global__ __launch_bounds__(256, 2) void combine_kernel(
    const float* __restrict__ part_o,  // [8][KS][4096][64]
    const float* __restrict__ part_l,  // [8][KS][4096]
    const float* __restrict__ x,       // [8][64][4096]
    float* __restrict__ out,           // [8][64][4096]
    int nchunk)
{
    __shared__ float Of[64 * 65];
    const int tid = threadIdx.x;
    const int b = blockIdx.y;
    const int i0 = blockIdx.x * 64;
    const int row = tid >> 2;          // local n 0..63
    const int seg = tid & 3;           // 16-col segment

    float acc[16];
    #pragma unroll
    for (int k = 0; k < 16; ++k) acc[k] = 0.f;
    float lt = 0.f;

    for (int ch = 0; ch < nchunk; ++ch) {
        const size_t base = (size_t)(b * nchunk + ch) * NTOK + i0 + row;
        lt += part_l[base];
        const float* po = part_o + base * 64 + seg * 16;
        #pragma unroll
        for (int k = 0; k < 4; ++k) {
            float4 v = *(const float4*)(po + k * 4);
            acc[k*4+0] += v.x; acc[k*4+1] += v.y; acc[k*4+2] += v.z; acc[k*4+3] += v.w;
        }
    }
    const float inv = 1.f / lt;
    #pragma unroll
    for (int k = 0; k < 16; ++k) Of[row * 65 + seg * 16 + k] = acc[k] * inv;
    __syncthreads();

    const int c    = tid >> 2;
    const int part = tid & 3;
    const float* xrow = x   + ((size_t)b * CCH + c) * NTOK + i0 + part * 16;
    float*       orow = out + ((size_t)b * CCH + c) * NTOK + i0 + part * 16;
    #pragma unroll
    for (int i4 = 0; i4 < 4; ++i4) {
        float4 xv = *(const float4*)(xrow + i4 * 4);
        float4 ov;
        ov.x = Of[(part * 16 + i4 * 4 + 0) * 65 + c] + xv.x;
        ov.y = Of[(part * 16 + i4 * 4 + 1) * 65 + c] + xv.y;
        ov.z = Of[(part * 16 + i4 * 4 + 2) * 65 + c] + xv.z;
        ov.w = Of[(part * 16 + i4 * 4 + 3) * 65 + c] + xv.w;
        *(float4*)(orow + i4 * 4) = ov;
    }
}

// ---------------------------------------------------------------------------
extern "C" void kernel_launch(void* const* d_in, const int* in_sizes, int n_in,
                              void* d_out, int out_size, void* d_ws, size_t ws_size,
                              hipStream_t stream) {
    const float* x = (const float*)d_in[0];
    const float* w = (const float*)d_in[1];
    float* out = (float*)d_out;

    const size_t xT_elems = (size_t)8 * NTOK * CCH;         // 2M shorts = 4 MB
    unsigned short* xT = (unsigned short*)d_ws;
    unsigned short* sT = xT + xT_elems;
    char* rest = (char*)d_ws + 2 * xT_elems * sizeof(unsigned short);   // +8 MB

    int KS = 4;
    while (KS > 1) {
        size_t need = 2 * xT_elems * sizeof(unsigned short)
                    + (size_t)KS * ((size_t)8 * NTOK * CCH * 4 + (size_t)8 * NTOK * 4);
        if (need <= ws_size) break;
        KS >>= 1;
    }
    float* part_o = (float*)rest;
    float* part_l = (float*)(rest + (size_t)KS * 8 * NTOK * CCH * 4);

    dim3 gp(64, 8);
    prep_kernel<<<gp, 256, 0, stream>>>(x, w, xT, sT);
    dim3 gf(32, KS, 8);
    flash_kernel<<<gf, 256, 0, stream>>>(xT, sT, part_o, part_l, KS, NTOK / KS);
    dim3 gc(64, 8);
    combine_kernel<<<gc, 256, 0, stream>>>(part_o, part_l, x, out, KS);
}